// Round 2
// baseline (4616.063 us; speedup 1.0000x reference)
//
#include <hip/hip_runtime.h>
#include <cstdint>
#include <cstddef>

#define B_   2
#define N_   8192
#define M_   2048
#define K_   32
#define C0_  64
#define C1_  128
#define C2_  256
#define CIN_ 67

// Exact-match distance: reference computes sum((a-b)**2, axis=-1) in f32 as
// ((dx^2 + dy^2) + dz^2) with no FMA contraction. _rn intrinsics forbid
// contract-fast fma fusion (would flip argmax / radius-boundary decisions).
__device__ __forceinline__ float sqdist_rn(float ax, float ay, float az,
                                           float bx, float by, float bz) {
  float dx = __fsub_rn(ax, bx);
  float dy = __fsub_rn(ay, by);
  float dz = __fsub_rn(az, bz);
  return __fadd_rn(__fadd_rn(__fmul_rn(dx, dx), __fmul_rn(dy, dy)),
                   __fmul_rn(dz, dz));
}

// ---------------------------------------------------------------------------
// 1) Furthest point sampling. One block (256 threads, 4 waves) per batch.
//    Thread t owns points p = k*256+t, k<32 (coords + min-dist in registers).
//    Single barrier per iteration: each wave reduces (dist, idx) via shfl
//    butterfly, attaches winner coords (uniform-k register select + shfl from
//    owner lane), publishes 5 values to double-buffered LDS slots; after ONE
//    barrier every thread picks the block winner from 4 candidates.
//    Tie-break == jnp.argmax first-occurrence (max dist, then min index).
// ---------------------------------------------------------------------------
__global__ __launch_bounds__(256, 1) void fps_kernel(const float* __restrict__ xyz,
                                                     float* __restrict__ new_xyz) {
  const int b = blockIdx.x;
  const int t = threadIdx.x;
  const float* xb = xyz + (size_t)b * N_ * 3;

  __shared__ float rD[2][4], rX[2][4], rY[2][4], rZ[2][4];
  __shared__ int rI[2][4];

  float px[32], py[32], pz[32], d[32];
#pragma unroll
  for (int k = 0; k < 32; ++k) {
    int p = k * 256 + t;
    px[k] = xb[p * 3 + 0];
    py[k] = xb[p * 3 + 1];
    pz[k] = xb[p * 3 + 2];
    d[k] = 1e10f;  // == f32(10000000000.0), matches jnp init exactly
  }

  float lx = xb[0], ly = xb[1], lz = xb[2];  // first selected index = 0
  if (t == 0) {
    new_xyz[(size_t)b * M_ * 3 + 0] = lx;
    new_xyz[(size_t)b * M_ * 3 + 1] = ly;
    new_xyz[(size_t)b * M_ * 3 + 2] = lz;
  }
  const int lane = t & 63, wid = t >> 6;

  for (int it = 1; it < M_; ++it) {
    float bd = -1.0f;
    int bi = 0;
#pragma unroll
    for (int k = 0; k < 32; ++k) {
      float dist = sqdist_rn(px[k], py[k], pz[k], lx, ly, lz);
      float dm = fminf(d[k], dist);
      d[k] = dm;
      bool take = dm > bd;  // strict: ascending p within thread -> first-occur
      bd = take ? dm : bd;
      bi = take ? (k * 256 + t) : bi;
    }
    // wave-64 argmax butterfly (all lanes converge to wave winner)
#pragma unroll
    for (int off = 32; off > 0; off >>= 1) {
      float od = __shfl_xor(bd, off);
      int oi = __shfl_xor(bi, off);
      if (od > bd || (od == bd && oi < bi)) { bd = od; bi = oi; }
    }
    // winner coords: k index is wave-uniform; every lane selects its own
    // candidate, then shfl from the owner lane (owner is in this wave).
    {
      int kk = bi >> 8;
      float cx = px[0], cy = py[0], cz = pz[0];
#pragma unroll
      for (int k2 = 1; k2 < 32; ++k2) {
        bool sel = (kk == k2);
        cx = sel ? px[k2] : cx;
        cy = sel ? py[k2] : cy;
        cz = sel ? pz[k2] : cz;
      }
      int ol = bi & 63;
      cx = __shfl(cx, ol);
      cy = __shfl(cy, ol);
      cz = __shfl(cz, ol);
      const int pb = it & 1;  // double-buffer: next iter writes other slot
      if (lane == 0) {
        rD[pb][wid] = bd; rI[pb][wid] = bi;
        rX[pb][wid] = cx; rY[pb][wid] = cy; rZ[pb][wid] = cz;
      }
    }
    __syncthreads();
    {
      const int pb = it & 1;
      float wbd = rD[pb][0];
      int wbi = rI[pb][0];
      float nx = rX[pb][0], ny = rY[pb][0], nz = rZ[pb][0];
#pragma unroll
      for (int j = 1; j < 4; ++j) {
        float od = rD[pb][j];
        int oi = rI[pb][j];
        if (od > wbd || (od == wbd && oi < wbi)) {
          wbd = od; wbi = oi;
          nx = rX[pb][j]; ny = rY[pb][j]; nz = rZ[pb][j];
        }
      }
      lx = nx; ly = ny; lz = nz;
    }
    if (t == 0) {
      new_xyz[((size_t)b * M_ + it) * 3 + 0] = lx;
      new_xyz[((size_t)b * M_ + it) * 3 + 1] = ly;
      new_xyz[((size_t)b * M_ + it) * 3 + 2] = lz;
    }
  }
}

// ---------------------------------------------------------------------------
// 2) Fused ball-query + grouping + MLP(67->128 relu ->256) + max over K.
//    One block (256 thr) per centroid. Ball query: wave w scans index chunk
//    [w*2048,(w+1)*2048) in order, ballot-appends first <=32 valid to its own
//    LDS list; lists concat in wave order == global index order (pointnet2
//    first-K semantics). Writes pre-BN pooled features TRANSPOSED into the
//    final (B,C2,M) output region (no scratch needed).
//    ws footprint of the whole pipeline: 2 KB (BN stats only).
// ---------------------------------------------------------------------------
__global__ __launch_bounds__(256) void mlp_kernel(const float* __restrict__ xyz,
                                                  const float* __restrict__ x,
                                                  const float* __restrict__ W1,
                                                  const float* __restrict__ b1,
                                                  const float* __restrict__ W2,
                                                  const float* __restrict__ b2,
                                                  const float* __restrict__ new_xyz,
                                                  float* __restrict__ outp) {
  __shared__ float sGRed[32 * 69];   // group tile; unioned w/ 8x256 max-red
  __shared__ float sU[128 * 69];     // W1 staged; unioned w/ 32x256 W2 tile
  __shared__ float sH1[32 * 132];
  __shared__ int sWIdx[4][K_];
  __shared__ int sWCnt[4];
  __shared__ int sIdx[K_];
  __shared__ float sQ[3];

  const int gm = blockIdx.x;
  const int b = gm >> 11;    // M_ = 2048
  const int m = gm & 2047;
  const int t = threadIdx.x;
  const int lane = t & 63;
  const int w = t >> 6;
  const float* xb = xyz + (size_t)b * N_ * 3;

  if (t < 3) sQ[t] = new_xyz[(size_t)gm * 3 + t];
  __syncthreads();
  const float qx = sQ[0], qy = sQ[1], qz = sQ[2];
  // (float)(0.1*0.1) = 0x3C23D70A; 0.1f*0.1f rounds differently — wrong.
  const float R2 = (float)(0.1 * 0.1);

  // ---- ball query ----
  {
    int cnt = 0;
    const int cbeg = w * 2048, cend = cbeg + 2048;
    for (int base = cbeg; base < cend; base += 64) {
      int p = base + lane;
      float d2 = sqdist_rn(qx, qy, qz, xb[p * 3 + 0], xb[p * 3 + 1], xb[p * 3 + 2]);
      bool valid = d2 < R2;
      unsigned long long mask = __ballot(valid);
      if (valid) {
        int pos = cnt + __popcll(mask & ((1ull << lane) - 1ull));
        if (pos < K_) sWIdx[w][pos] = p;
      }
      cnt += __popcll(mask);
      if (cnt >= K_) break;  // wave-uniform
    }
    if (lane == 0) sWCnt[w] = (cnt < K_) ? cnt : K_;
  }
  __syncthreads();
  if (t < K_) {
    int c0 = sWCnt[0], c1 = sWCnt[1], c2 = sWCnt[2], c3 = sWCnt[3];
    int s1 = c0 + c1, s2 = s1 + c2, s3 = s2 + c3;
    int j = t, idx;
    if (j < c0) idx = sWIdx[0][j];
    else if (j < s1) idx = sWIdx[1][j - c0];
    else if (j < s2) idx = sWIdx[2][j - s1];
    else if (j < s3) idx = sWIdx[3][j - s2];
    else {
      int fw = c0 ? 0 : (c1 ? 1 : (c2 ? 2 : 3));
      idx = (s3 > 0) ? sWIdx[fw][0] : 0;  // fill with first valid index
    }
    sIdx[j] = idx;
  }
  __syncthreads();

  // ---- grouping: rel coords + features into sGRed (32 x 69 padded) ----
  if (t < K_) {
    int id = sIdx[t];
    sGRed[t * 69 + 0] = xb[id * 3 + 0] - qx;
    sGRed[t * 69 + 1] = xb[id * 3 + 1] - qy;
    sGRed[t * 69 + 2] = xb[id * 3 + 2] - qz;
  }
  {
    int r = t & 31;
    int c0 = (t >> 5) * 8;
    int id = sIdx[r];
    const float* xf = x + ((size_t)b * C0_ + c0) * N_ + id;
#pragma unroll
    for (int j = 0; j < 8; ++j) sGRed[r * 69 + 3 + c0 + j] = xf[(size_t)j * N_];
  }
  for (int i = t; i < C1_ * CIN_; i += 256) {
    sU[(i / CIN_) * 69 + (i % CIN_)] = W1[i];
  }
  __syncthreads();

  const int ol = t & 31;  // output-lane: o = ol + 32*j
  const int rg = t >> 5;  // row group: rows rg*4 .. rg*4+3

  // ---- layer 1: h1 = relu(G @ W1^T + b1), 4 rows x 4 outs per thread ----
  float acc[4][4] = {{0.f}};
  for (int c = 0; c < CIN_; ++c) {
    float g[4], wv[4];
#pragma unroll
    for (int i = 0; i < 4; ++i) g[i] = sGRed[(rg * 4 + i) * 69 + c];
#pragma unroll
    for (int j = 0; j < 4; ++j) wv[j] = sU[(ol + 32 * j) * 69 + c];
#pragma unroll
    for (int i = 0; i < 4; ++i)
#pragma unroll
      for (int j = 0; j < 4; ++j) acc[i][j] += g[i] * wv[j];
  }
#pragma unroll
  for (int j = 0; j < 4; ++j) {
    float bias = b1[ol + 32 * j];
#pragma unroll
    for (int i = 0; i < 4; ++i) {
      float v = acc[i][j] + bias;
      sH1[(rg * 4 + i) * 132 + ol + 32 * j] = fmaxf(v, 0.0f);
    }
  }

  // ---- layer 2: h2 = h1 @ W2^T, 4 rows x 8 outs per thread ----
  float acc2[4][8] = {{0.f}};
  for (int ct = 0; ct < 4; ++ct) {
    __syncthreads();  // sU reuse safe; (ct==0) also covers sH1 writes
    const float4* w4 = (const float4*)(W2 + (size_t)t * C1_ + ct * 32);
#pragma unroll
    for (int jj = 0; jj < 8; ++jj) {
      float4 v = w4[jj];
      sU[(jj * 4 + 0) * 256 + t] = v.x;
      sU[(jj * 4 + 1) * 256 + t] = v.y;
      sU[(jj * 4 + 2) * 256 + t] = v.z;
      sU[(jj * 4 + 3) * 256 + t] = v.w;
    }
    __syncthreads();
    for (int cc = 0; cc < 32; ++cc) {
      float h[4], wv[8];
#pragma unroll
      for (int i = 0; i < 4; ++i) h[i] = sH1[(rg * 4 + i) * 132 + ct * 32 + cc];
#pragma unroll
      for (int j = 0; j < 8; ++j) wv[j] = sU[cc * 256 + ol + 32 * j];
#pragma unroll
      for (int i = 0; i < 4; ++i)
#pragma unroll
        for (int j = 0; j < 8; ++j) acc2[i][j] += h[i] * wv[j];
    }
  }

  // ---- max over K, + b2 (max(x)+c == max(x+c): RN is monotone) ----
  __syncthreads();  // group tile dead; reuse sGRed as reduction buffer
#pragma unroll
  for (int j = 0; j < 8; ++j) {
    float pm = acc2[0][j];
#pragma unroll
    for (int i = 1; i < 4; ++i) pm = fmaxf(pm, acc2[i][j]);
    sGRed[rg * 256 + ol + 32 * j] = pm;
  }
  __syncthreads();
  {
    int o = t;
    float v = sGRed[o];
#pragma unroll
    for (int g = 1; g < 8; ++g) v = fmaxf(v, sGRed[g * 256 + o]);
    v += b2[o];
    // transposed store into final (B, C2, M) layout (pre-BN)
    outp[((size_t)(b * C2_ + o)) * M_ + m] = v;
  }
}

// ---------------------------------------------------------------------------
// 3) BN stats per channel (deterministic, double accum). One block / channel.
//    Reads are channel-contiguous in the (B,C2,M) layout.
// ---------------------------------------------------------------------------
__global__ __launch_bounds__(256) void bn_stats_kernel(const float* __restrict__ outp,
                                                       const float* __restrict__ gamma,
                                                       float* __restrict__ stats) {
  const int o = blockIdx.x;
  const int t = threadIdx.x;
  double s = 0.0, s2 = 0.0;
  for (int b = 0; b < B_; ++b) {
    const float* p = outp + ((size_t)(b * C2_ + o)) * M_;
    for (int i = t; i < M_; i += 256) {
      float v = p[i];
      s += (double)v;
      s2 += (double)v * (double)v;
    }
  }
#pragma unroll
  for (int off = 32; off > 0; off >>= 1) {
    s += __shfl_xor(s, off);
    s2 += __shfl_xor(s2, off);
  }
  __shared__ double aS[4], aS2[4];
  if ((t & 63) == 0) { aS[t >> 6] = s; aS2[t >> 6] = s2; }
  __syncthreads();
  if (t == 0) {
    double S = aS[0] + aS[1] + aS[2] + aS[3];
    double S2 = aS2[0] + aS2[1] + aS2[2] + aS2[3];
    double mean = S / (double)(B_ * M_);
    double var = S2 / (double)(B_ * M_) - mean * mean;
    float rstd = 1.0f / sqrtf((float)var + 1e-5f);
    stats[o] = (float)mean;
    stats[C2_ + o] = gamma[o] * rstd;
  }
}

// ---------------------------------------------------------------------------
// 4) BN apply, in place on the (B,C2,M) output region. float4-vectorized.
// ---------------------------------------------------------------------------
__global__ __launch_bounds__(256) void bn_apply_kernel(float* __restrict__ outp,
                                                       const float* __restrict__ stats,
                                                       const float* __restrict__ beta) {
  const int i4 = blockIdx.x * 256 + threadIdx.x;  // B_*C2_*M_/4 = 262144
  const int ch = (i4 >> 9) & 255;                 // M_/4 = 512 float4 / chan
  const float mean = stats[ch];
  const float scale = stats[C2_ + ch];
  const float bt = beta[ch];
  float4 v = ((const float4*)outp)[i4];
  v.x = (v.x - mean) * scale + bt;
  v.y = (v.y - mean) * scale + bt;
  v.z = (v.z - mean) * scale + bt;
  v.w = (v.w - mean) * scale + bt;
  ((float4*)outp)[i4] = v;
}

// ---------------------------------------------------------------------------
extern "C" void kernel_launch(void* const* d_in, const int* in_sizes, int n_in,
                              void* d_out, int out_size, void* d_ws, size_t ws_size,
                              hipStream_t stream) {
  const float* xyz   = (const float*)d_in[0];
  const float* x     = (const float*)d_in[1];
  const float* W1    = (const float*)d_in[2];
  const float* b1    = (const float*)d_in[3];
  const float* W2    = (const float*)d_in[4];
  const float* b2    = (const float*)d_in[5];
  const float* gamma = (const float*)d_in[6];
  const float* beta  = (const float*)d_in[7];

  float* new_xyz = (float*)d_out;                       // (B, M, 3)
  float* outp    = (float*)d_out + (size_t)B_ * M_ * 3; // (B, C2, M)
  float* stats   = (float*)d_ws;                        // 2*C2 floats = 2 KB

  fps_kernel<<<B_, 256, 0, stream>>>(xyz, new_xyz);
  mlp_kernel<<<B_ * M_, 256, 0, stream>>>(xyz, x, W1, b1, W2, b2, new_xyz, outp);
  bn_stats_kernel<<<C2_, 256, 0, stream>>>(outp, gamma, stats);
  bn_apply_kernel<<<(B_ * C2_ * M_ / 4) / 256, 256, 0, stream>>>(outp, stats, beta);
}